// Round 5
// baseline (349.554 us; speedup 1.0000x reference)
//
#include <hip/hip_runtime.h>

// Problem constants (match reference)
constexpr int HEADS  = 8;
constexpr int DIM    = 64;
constexpr int NREAL  = 30000;
constexpr int NVIRT  = 2000;
constexpr int NNODES = NREAL + NVIRT;   // 32000
constexpr int NEDGES = 512000;          // == NNODES * 16 (exploited in k_prep)
constexpr int STRIDE = 64;  // max tracked in-degree; Poisson(16): P(deg>64) ~ 1e-18

// Owner-block bucketing geometry
constexpr int NSTAGE   = 2000;          // staging blocks (ndata fp32->fp16)
constexpr int NBUCKET  = 256;           // bucket blocks, each owns NNODES/NBUCKET nodes
constexpr int NPB      = NNODES / NBUCKET;   // 125 nodes per bucket block
// virtual nodes start at 30000 = 125*240 -> blocks 240..255 own exactly the virtual range

typedef _Float16 half4 __attribute__((ext_vector_type(4)));

// ---------------- kernels ----------------

// Pre-pass (replaces the memset dispatch):
//  - convert dst int32 -> ushort (halves the stream traffic for bucketing;
//    dst < 32000 always fits). dst16 aliases new_nft's first 1MB (dead until agg1).
//  - zero mark (32000 bytes = 8000 uints)
__global__ __launch_bounds__(256) void k_pre(const int* __restrict__ dst,
                                             unsigned short* __restrict__ dst16,
                                             unsigned int* __restrict__ mark32) {
  int t = blockIdx.x * 256 + threadIdx.x;   // 500 blocks = 128000 threads
  if (t < NEDGES / 4) {
    int4 v = ((const int4*)dst)[t];
    ushort4 w = make_ushort4((unsigned short)v.x, (unsigned short)v.y,
                             (unsigned short)v.z, (unsigned short)v.w);
    ((ushort4*)dst16)[t] = w;
  }
  if (t < NNODES / 4) mark32[t] = 0;
}

// Fused staging + owner-block bucketing. NO global atomics (round-3/4 evidence:
// 512k device-scope atomicAdds = ~24MB fabric write traffic and ~25us of k_prep).
//  - blocks [0, NSTAGE): thread i stages half4 #(i&15) of node i>>4 into ndata
//  - blocks [NSTAGE, NSTAGE+NBUCKET): block owns nodes [125b, 125b+125); streams
//    all dst16, buckets in-range edges via LDS atomics into an LDS slot buffer,
//    then writes slots + cnt coalesced as single writer (cnt needs no pre-zero).
//    Virtual-owner blocks (base >= NREAL) also set mark[src] for their edges.
__global__ __launch_bounds__(256) void k_prep(const float* __restrict__ features,
                                              const float* __restrict__ virtue,
                                              const int* __restrict__ cnodes,
                                              const int* __restrict__ src,
                                              const unsigned short* __restrict__ dst16,
                                              _Float16* __restrict__ ndata,
                                              int* __restrict__ cnt,
                                              unsigned char* __restrict__ mark,
                                              unsigned short* __restrict__ slots) {
  __shared__ int            cntloc[NPB];
  __shared__ unsigned short slotbuf[NPB * STRIDE];   // 16000 B

  if (blockIdx.x < NSTAGE) {
    // ---- staging path (identical numerics to verified rounds) ----
    int i = blockIdx.x * 256 + threadIdx.x;          // 0..NEDGES-1
    int node = i >> 4;
    int q    = i & 15;
    const float4* srcp = (node < NREAL)
        ? (const float4*)(features + (long)cnodes[node] * DIM)
        : (const float4*)(virtue + (long)(node - NREAL) * DIM);
    float4 v = srcp[q];
    half4 h = { (_Float16)v.x, (_Float16)v.y, (_Float16)v.z, (_Float16)v.w };
    ((half4*)(ndata + (long)node * DIM))[q] = h;
    return;
  }

  // ---- bucket path ----
  int b    = blockIdx.x - NSTAGE;
  int base = b * NPB;
  bool isVirtOwner = (base >= NREAL);   // block-uniform

  if (threadIdx.x < NPB) cntloc[threadIdx.x] = 0;
  __syncthreads();

  const ushort4* d4 = (const ushort4*)dst16;
  constexpr int ITERS = NEDGES / (256 * 4);   // 500
  for (int it = 0; it < ITERS; ++it) {
    int v4 = it * 256 + threadIdx.x;          // ushort4 index, coalesced
    ushort4 dv = d4[v4];
    int e0 = v4 * 4;
#pragma unroll
    for (int j = 0; j < 4; ++j) {
      int d = (j == 0) ? dv.x : (j == 1) ? dv.y : (j == 2) ? dv.z : dv.w;
      unsigned r = (unsigned)(d - base);
      if (r < (unsigned)NPB) {
        int s = src[e0 + j];
        int pos = atomicAdd(&cntloc[r], 1);   // LDS atomic: on-CU, cheap
        if (pos < STRIDE) slotbuf[r * STRIDE + pos] = (unsigned short)s;
        if (isVirtOwner) mark[s] = 1;         // racy but idempotent
      }
    }
  }
  __syncthreads();

  // single-writer coalesced write-out: 125 rows x 128B = 4000 uints
  unsigned int* gslots = (unsigned int*)(slots + (long)base * STRIDE);
  const unsigned int* lsl = (const unsigned int*)slotbuf;
  for (int k = threadIdx.x; k < NPB * STRIDE / 2; k += 256) gslots[k] = lsl[k];
  if (threadIdx.x < NPB) cnt[base + threadIdx.x] = cntloc[threadIdx.x];
}

// Round 1: one wave per dst node (skipped unless needed by round 2).
// Lane layout: q = lane>>4 (edge sub-slot), l = lane&15 (8B fp16 chunk = dims 4l..4l+3).
// Verified in round 4 (head loads issued together; inner loop fully unrolled).
__global__ __launch_bounds__(256) void k_agg1(const int* __restrict__ cnt,
                                              const unsigned char* __restrict__ mark,
                                              const unsigned short* __restrict__ slots,
                                              const _Float16* __restrict__ ndata,
                                              float* __restrict__ new_nft) {
  int node = blockIdx.x * 4 + (threadIdx.x >> 6);
  if (node >= NNODES) return;
  int lane = threadIdx.x & 63;
  int q = lane >> 4;
  int l = lane & 15;
  unsigned char m = mark[node];
  int deg = cnt[node];
  int myidx = (int)slots[(long)node * STRIDE + lane];  // always-allocated row
  if (!m) return;                   // wave-uniform exit (not read by round 2)
  if (deg > STRIDE) deg = STRIDE;
  float4 acc  = make_float4(0.f, 0.f, 0.f, 0.f);
  float4 acc2 = make_float4(0.f, 0.f, 0.f, 0.f);
  const half4* nd = (const half4*)ndata;
#pragma unroll
  for (int u = 0; u < 8; ++u) {
    int ka = u * 8 + q;
    int kb = u * 8 + q + 4;
    int sa = __shfl(myidx, ka);
    int sb = __shfl(myidx, kb);
    if (ka < deg) {
      half4 v = nd[(long)sa * 16 + l];
      acc.x += (float)v.x; acc.y += (float)v.y; acc.z += (float)v.z; acc.w += (float)v.w;
    }
    if (kb < deg) {
      half4 v = nd[(long)sb * 16 + l];
      acc2.x += (float)v.x; acc2.y += (float)v.y; acc2.z += (float)v.z; acc2.w += (float)v.w;
    }
  }
  acc.x += acc2.x; acc.y += acc2.y; acc.z += acc2.z; acc.w += acc2.w;
  acc.x += __shfl_xor(acc.x, 16); acc.y += __shfl_xor(acc.y, 16);
  acc.z += __shfl_xor(acc.z, 16); acc.w += __shfl_xor(acc.w, 16);
  acc.x += __shfl_xor(acc.x, 32); acc.y += __shfl_xor(acc.y, 32);
  acc.z += __shfl_xor(acc.z, 32); acc.w += __shfl_xor(acc.w, 32);
  if (q == 0) {
    float inv = (deg > 0) ? 1.0f / (float)deg : 0.0f;
    acc.x *= inv; acc.y *= inv; acc.z *= inv; acc.w *= inv;
    ((float4*)new_nft)[(long)node * 16 + l] = acc;
  }
}

// Round 2: only virtual nodes reach the output; replicate across 8 heads.
__global__ __launch_bounds__(256) void k_agg2(const int* __restrict__ cnt,
                                              const unsigned short* __restrict__ slots,
                                              const float* __restrict__ new_nft,
                                              float* __restrict__ out) {
  int v = blockIdx.x * 4 + (threadIdx.x >> 6);
  if (v >= NVIRT) return;
  int node = NREAL + v;
  int lane = threadIdx.x & 63;
  int q = lane >> 4;
  int l = lane & 15;
  int deg = cnt[node];
  int myidx = (int)slots[(long)node * STRIDE + lane];
  if (deg > STRIDE) deg = STRIDE;
  float4 acc  = make_float4(0.f, 0.f, 0.f, 0.f);
  float4 acc2 = make_float4(0.f, 0.f, 0.f, 0.f);
  const float4* nf4 = (const float4*)new_nft;
#pragma unroll
  for (int u = 0; u < 8; ++u) {
    int ka = u * 8 + q;
    int kb = u * 8 + q + 4;
    int sa = __shfl(myidx, ka);
    int sb = __shfl(myidx, kb);
    if (ka < deg) {
      float4 x = nf4[(long)sa * 16 + l];
      acc.x += x.x; acc.y += x.y; acc.z += x.z; acc.w += x.w;
    }
    if (kb < deg) {
      float4 x = nf4[(long)sb * 16 + l];
      acc2.x += x.x; acc2.y += x.y; acc2.z += x.z; acc2.w += x.w;
    }
  }
  acc.x += acc2.x; acc.y += acc2.y; acc.z += acc2.z; acc.w += acc2.w;
  acc.x += __shfl_xor(acc.x, 16); acc.y += __shfl_xor(acc.y, 16);
  acc.z += __shfl_xor(acc.z, 16); acc.w += __shfl_xor(acc.w, 16);
  acc.x += __shfl_xor(acc.x, 32); acc.y += __shfl_xor(acc.y, 32);
  acc.z += __shfl_xor(acc.z, 32); acc.w += __shfl_xor(acc.w, 32);
  if (q == 0) {
    float inv = (deg > 0) ? 1.0f / (float)deg : 0.0f;
    acc.x *= inv; acc.y *= inv; acc.z *= inv; acc.w *= inv;
    float4* o4 = (float4*)out;
#pragma unroll
    for (int h = 0; h < HEADS; ++h)
      o4[((long)v * HEADS + h) * 16 + l] = acc;
  }
}

// ---------------- launch ----------------

extern "C" void kernel_launch(void* const* d_in, const int* in_sizes, int n_in,
                              void* d_out, int out_size, void* d_ws, size_t ws_size,
                              hipStream_t stream) {
  const float* features = (const float*)d_in[0];   // [VOCAB, 64]
  const float* virtue   = (const float*)d_in[1];   // [NVIRT, 64]
  const int*   cnodes   = (const int*)d_in[2];     // [NREAL]
  const int*   src      = (const int*)d_in[3];     // [NEDGES]
  const int*   dst      = (const int*)d_in[4];     // [NEDGES]
  float* out = (float*)d_out;                      // [NVIRT, 8, 64] fp32

  // workspace layout
  float*          new_nft = (float*)d_ws;                              // [NNODES*DIM] fp32, 8.19 MB
  _Float16*       ndata   = (_Float16*)(new_nft + (long)NNODES * DIM); // [NNODES*DIM] fp16, 4.10 MB
  int*            cnt     = (int*)(ndata + (long)NNODES * DIM);        // [NNODES]
  unsigned char*  mark    = (unsigned char*)(cnt + NNODES);            // [NNODES]
  unsigned short* slots   = (unsigned short*)(mark + NNODES);          // [NNODES*STRIDE] 4.10 MB
  // dst16 aliases new_nft's first 1 MB: dead until k_agg1, consumed by end of k_prep
  unsigned short* dst16   = (unsigned short*)new_nft;                  // [NEDGES] 1.02 MB

  const int B = 256;

  k_pre<<<500, B, 0, stream>>>(dst, dst16, (unsigned int*)mark);
  k_prep<<<NSTAGE + NBUCKET, B, 0, stream>>>(features, virtue, cnodes, src,
                                             dst16, ndata, cnt, mark, slots);
  k_agg1<<<(NNODES + 3) / 4, B, 0, stream>>>(cnt, mark, slots, ndata, new_nft);
  k_agg2<<<(NVIRT + 3) / 4, B, 0, stream>>>(cnt, slots, new_nft, out);
}

// Round 6
// 121.567 us; speedup vs baseline: 2.8754x; 2.8754x over previous
//
#include <hip/hip_runtime.h>

// Problem constants (match reference)
constexpr int HEADS  = 8;
constexpr int DIM    = 64;
constexpr int NREAL  = 30000;
constexpr int NVIRT  = 2000;
constexpr int NNODES = NREAL + NVIRT;   // 32000
constexpr int NEDGES = 512000;
constexpr int STRIDE = 64;  // max tracked in-degree; Poisson(16): P(deg>64) ~ 1e-18

// Two-level CSR build geometry
constexpr int NSTAGE  = 2000;  // staging blocks in k_prep (verified path)
constexpr int NBINBLK = 250;   // binning blocks in k_prep, 2048 edges each
constexpr int NBIN    = 256;   // dst bins; bin = dst/125
constexpr int NPB     = 125;   // nodes per bin (256*125 = 32000)
constexpr int CAP     = 48;    // partition cell capacity; cell load ~Poisson(8), P(>48)~1e-22

typedef _Float16 half4 __attribute__((ext_vector_type(4)));

// ---------------- kernels ----------------

// k_prep: staging (blocks 0..1999, verified numerics) + edge partitioning
// (blocks 2000..2249). NO global atomics anywhere (round-3/4 evidence: 512k
// device-scope returning atomics + scattered stores = ~27MB fabric traffic and
// a latency-bound ~40us kernel). Each binning block owns edges [b*2048,
// (b+1)*2048) and scatters them into statically-owned partition cells
// part[(bin*256+b)*CAP ...] — ownership replaces atomic reservation.
// Also zeroes mark (written by k_bin2, read by k_agg1). cnt needs no zeroing
// (fully written by k_bin2) -> the memset dispatch is gone.
__global__ __launch_bounds__(256) void k_prep(const float* __restrict__ features,
                                              const float* __restrict__ virtue,
                                              const int* __restrict__ cnodes,
                                              const int* __restrict__ src,
                                              const int* __restrict__ dst,
                                              _Float16* __restrict__ ndata,
                                              unsigned short* __restrict__ gHist,
                                              unsigned int* __restrict__ part,
                                              unsigned int* __restrict__ mark32) {
  if (blockIdx.x < NSTAGE) {
    // ---- staging path (identical numerics to all verified rounds) ----
    int i = blockIdx.x * 256 + threadIdx.x;          // 0..NEDGES-1
    int node = i >> 4;
    int q    = i & 15;
    const float4* srcp = (node < NREAL)
        ? (const float4*)(features + (long)cnodes[node] * DIM)
        : (const float4*)(virtue + (long)(node - NREAL) * DIM);
    float4 v = srcp[q];
    half4 h = { (_Float16)v.x, (_Float16)v.y, (_Float16)v.z, (_Float16)v.w };
    ((half4*)(ndata + (long)node * DIM))[q] = h;
    return;
  }

  // ---- binning path: one block owns 2048 contiguous edges ----
  __shared__ unsigned int hist[NBIN];
  __shared__ unsigned int cur[NBIN];
  int b   = blockIdx.x - NSTAGE;    // 0..249
  int tid = threadIdx.x;

  // fold mark zeroing into the first 32 binning blocks (mark = 8000 u32)
  if (b < 32) {
    int t32 = b * 256 + tid;
    if (t32 < NNODES / 4) mark32[t32] = 0;
  }

  hist[tid] = 0;
  __syncthreads();

  int e0 = b * 2048 + tid * 8;      // 8 edges per thread, 32B-aligned int4 loads
  int4 sa = *(const int4*)(src + e0);
  int4 sb = *(const int4*)(src + e0 + 4);
  int4 da = *(const int4*)(dst + e0);
  int4 db = *(const int4*)(dst + e0 + 4);
  int ds8[8] = { da.x, da.y, da.z, da.w, db.x, db.y, db.z, db.w };
  int ss8[8] = { sa.x, sa.y, sa.z, sa.w, sb.x, sb.y, sb.z, sb.w };
  int bn8[8];
#pragma unroll
  for (int j = 0; j < 8; ++j) {
    bn8[j] = ds8[j] / NPB;                  // compiler emits magic-mul for /125
    atomicAdd(&hist[bn8[j]], 1u);           // LDS atomic: on-CU
  }
  __syncthreads();

  // publish per-cell counts; init per-bin cursors to this block's cell base
  gHist[tid * 256 + b] = (unsigned short)hist[tid];
  cur[tid] = ((unsigned)tid * 256u + (unsigned)b) * CAP;
  __syncthreads();

#pragma unroll
  for (int j = 0; j < 8; ++j) {
    unsigned p   = atomicAdd(&cur[bn8[j]], 1u);   // LDS atomic
    unsigned lim = ((unsigned)bn8[j] * 256u + (unsigned)b) * CAP + CAP;
    if (p < lim)                                   // overflow guard (P~1e-17)
      part[p] = ((unsigned)ds8[j] << 15) | (unsigned)ss8[j];
  }
}

// k_bin2: block B owns dst nodes [B*125, B*125+125). Reads ONLY its bin's
// partition cells (~2048 edges, chunk-coalesced), LDS-buckets them (round-5
// verified slotbuf scheme), then single-writer coalesced writes slots + cnt.
// Sets mark[src]=1 for virtual-dst edges (bins 240..255 only, by construction).
__global__ __launch_bounds__(256) void k_bin2(const unsigned short* __restrict__ gHist,
                                              const unsigned int* __restrict__ part,
                                              int* __restrict__ cnt,
                                              unsigned char* __restrict__ mark,
                                              unsigned short* __restrict__ slots) {
  __shared__ unsigned short slotbuf[NPB * STRIDE];   // 16000 B
  __shared__ int            cntloc[NPB];
  __shared__ unsigned int   pre[257];

  int B = blockIdx.x, tid = threadIdx.x;
  if (tid < NPB) cntloc[tid] = 0;

  // cell counts for this bin (coalesced u16 row read), clamp to CAP
  unsigned c = (tid < NBINBLK) ? (unsigned)gHist[B * 256 + tid] : 0u;
  if (c > CAP) c = CAP;
  pre[tid + 1] = c;
  if (tid == 0) pre[0] = 0;
  __syncthreads();
  // Hillis-Steele inclusive scan over pre[1..256]
  for (int off = 1; off < 256; off <<= 1) {
    unsigned v = 0;
    if (tid >= off) v = pre[tid + 1 - off];
    __syncthreads();
    pre[tid + 1] += v;
    __syncthreads();
  }
  unsigned T = pre[256];                 // total edges in this bin (~2048)
  int base0 = B * NPB;

  for (unsigned t = tid; t < T; t += 256) {
    // find cell: largest blk with pre[blk] <= t  (binary search, LDS broadcast)
    int lo = 0, hi = 255;
    while (lo < hi) { int mid = (lo + hi + 1) >> 1; if (pre[mid] <= t) lo = mid; else hi = mid - 1; }
    unsigned w = part[((unsigned)B * 256u + (unsigned)lo) * CAP + (t - pre[lo])];
    int d = (int)(w >> 15);
    int s = (int)(w & 0x7fffu);
    int r = d - base0;                            // in [0,125) by construction
    int pos = atomicAdd(&cntloc[r], 1);           // LDS atomic
    if (pos < STRIDE) slotbuf[r * STRIDE + pos] = (unsigned short)s;
    if (d >= NREAL) mark[s] = 1;                  // racy but idempotent
  }
  __syncthreads();

  // single-writer coalesced write-out: 125 rows x 128B = 4000 u32
  unsigned int* gs = (unsigned int*)(slots + (long)base0 * STRIDE);
  const unsigned int* ls = (const unsigned int*)slotbuf;
  for (int k = tid; k < NPB * STRIDE / 2; k += 256) gs[k] = ls[k];
  if (tid < NPB) cnt[base0 + tid] = cntloc[tid];
}

// Round 1: one wave per dst node (skipped unless needed by round 2).
// Verified in rounds 0/4 (head loads issued together; inner loop fully unrolled).
__global__ __launch_bounds__(256) void k_agg1(const int* __restrict__ cnt,
                                              const unsigned char* __restrict__ mark,
                                              const unsigned short* __restrict__ slots,
                                              const _Float16* __restrict__ ndata,
                                              float* __restrict__ new_nft) {
  int node = blockIdx.x * 4 + (threadIdx.x >> 6);
  if (node >= NNODES) return;
  int lane = threadIdx.x & 63;
  int q = lane >> 4;
  int l = lane & 15;
  unsigned char m = mark[node];
  int deg = cnt[node];
  int myidx = (int)slots[(long)node * STRIDE + lane];  // always-allocated row
  if (!m) return;                   // wave-uniform exit (not read by round 2)
  if (deg > STRIDE) deg = STRIDE;
  float4 acc  = make_float4(0.f, 0.f, 0.f, 0.f);
  float4 acc2 = make_float4(0.f, 0.f, 0.f, 0.f);
  const half4* nd = (const half4*)ndata;
#pragma unroll
  for (int u = 0; u < 8; ++u) {
    int ka = u * 8 + q;
    int kb = u * 8 + q + 4;
    int sa = __shfl(myidx, ka);
    int sb = __shfl(myidx, kb);
    if (ka < deg) {
      half4 v = nd[(long)sa * 16 + l];
      acc.x += (float)v.x; acc.y += (float)v.y; acc.z += (float)v.z; acc.w += (float)v.w;
    }
    if (kb < deg) {
      half4 v = nd[(long)sb * 16 + l];
      acc2.x += (float)v.x; acc2.y += (float)v.y; acc2.z += (float)v.z; acc2.w += (float)v.w;
    }
  }
  acc.x += acc2.x; acc.y += acc2.y; acc.z += acc2.z; acc.w += acc2.w;
  acc.x += __shfl_xor(acc.x, 16); acc.y += __shfl_xor(acc.y, 16);
  acc.z += __shfl_xor(acc.z, 16); acc.w += __shfl_xor(acc.w, 16);
  acc.x += __shfl_xor(acc.x, 32); acc.y += __shfl_xor(acc.y, 32);
  acc.z += __shfl_xor(acc.z, 32); acc.w += __shfl_xor(acc.w, 32);
  if (q == 0) {
    float inv = (deg > 0) ? 1.0f / (float)deg : 0.0f;
    acc.x *= inv; acc.y *= inv; acc.z *= inv; acc.w *= inv;
    ((float4*)new_nft)[(long)node * 16 + l] = acc;
  }
}

// Round 2: only virtual nodes reach the output; replicate across 8 heads.
__global__ __launch_bounds__(256) void k_agg2(const int* __restrict__ cnt,
                                              const unsigned short* __restrict__ slots,
                                              const float* __restrict__ new_nft,
                                              float* __restrict__ out) {
  int v = blockIdx.x * 4 + (threadIdx.x >> 6);
  if (v >= NVIRT) return;
  int node = NREAL + v;
  int lane = threadIdx.x & 63;
  int q = lane >> 4;
  int l = lane & 15;
  int deg = cnt[node];
  int myidx = (int)slots[(long)node * STRIDE + lane];
  if (deg > STRIDE) deg = STRIDE;
  float4 acc  = make_float4(0.f, 0.f, 0.f, 0.f);
  float4 acc2 = make_float4(0.f, 0.f, 0.f, 0.f);
  const float4* nf4 = (const float4*)new_nft;
#pragma unroll
  for (int u = 0; u < 8; ++u) {
    int ka = u * 8 + q;
    int kb = u * 8 + q + 4;
    int sa = __shfl(myidx, ka);
    int sb = __shfl(myidx, kb);
    if (ka < deg) {
      float4 x = nf4[(long)sa * 16 + l];
      acc.x += x.x; acc.y += x.y; acc.z += x.z; acc.w += x.w;
    }
    if (kb < deg) {
      float4 x = nf4[(long)sb * 16 + l];
      acc2.x += x.x; acc2.y += x.y; acc2.z += x.z; acc2.w += x.w;
    }
  }
  acc.x += acc2.x; acc.y += acc2.y; acc.z += acc2.z; acc.w += acc2.w;
  acc.x += __shfl_xor(acc.x, 16); acc.y += __shfl_xor(acc.y, 16);
  acc.z += __shfl_xor(acc.z, 16); acc.w += __shfl_xor(acc.w, 16);
  acc.x += __shfl_xor(acc.x, 32); acc.y += __shfl_xor(acc.y, 32);
  acc.z += __shfl_xor(acc.z, 32); acc.w += __shfl_xor(acc.w, 32);
  if (q == 0) {
    float inv = (deg > 0) ? 1.0f / (float)deg : 0.0f;
    acc.x *= inv; acc.y *= inv; acc.z *= inv; acc.w *= inv;
    float4* o4 = (float4*)out;
#pragma unroll
    for (int h = 0; h < HEADS; ++h)
      o4[((long)v * HEADS + h) * 16 + l] = acc;
  }
}

// ---------------- launch ----------------

extern "C" void kernel_launch(void* const* d_in, const int* in_sizes, int n_in,
                              void* d_out, int out_size, void* d_ws, size_t ws_size,
                              hipStream_t stream) {
  const float* features = (const float*)d_in[0];   // [VOCAB, 64]
  const float* virtue   = (const float*)d_in[1];   // [NVIRT, 64]
  const int*   cnodes   = (const int*)d_in[2];     // [NREAL]
  const int*   src      = (const int*)d_in[3];     // [NEDGES]
  const int*   dst      = (const int*)d_in[4];     // [NEDGES]
  float* out = (float*)d_out;                      // [NVIRT, 8, 64] fp32

  // workspace layout (offsets all 16B-aligned)
  float*          new_nft = (float*)d_ws;                              // 8.192 MB
  _Float16*       ndata   = (_Float16*)(new_nft + (long)NNODES * DIM); // 4.096 MB
  int*            cnt     = (int*)(ndata + (long)NNODES * DIM);        // 128 KB
  unsigned char*  mark    = (unsigned char*)(cnt + NNODES);            // 32 KB
  unsigned short* slots   = (unsigned short*)(mark + NNODES);          // 4.096 MB
  unsigned short* gHist   = slots + (long)NNODES * STRIDE;             // [NBIN*256] u16, 128 KB
  unsigned int*   part    = (unsigned int*)(gHist + NBIN * 256);       // [NBIN*256*CAP] u32, 12.6 MB

  const int B = 256;

  k_prep<<<NSTAGE + NBINBLK, B, 0, stream>>>(features, virtue, cnodes, src, dst,
                                             ndata, gHist, part, (unsigned int*)mark);
  k_bin2<<<NBIN, B, 0, stream>>>(gHist, part, cnt, mark, slots);
  k_agg1<<<(NNODES + 3) / 4, B, 0, stream>>>(cnt, mark, slots, ndata, new_nft);
  k_agg2<<<(NVIRT + 3) / 4, B, 0, stream>>>(cnt, slots, new_nft, out);
}

// Round 7
// 119.864 us; speedup vs baseline: 2.9162x; 1.0142x over previous
//
#include <hip/hip_runtime.h>

// Problem constants (match reference)
constexpr int HEADS  = 8;
constexpr int DIM    = 64;
constexpr int NREAL  = 30000;
constexpr int NVIRT  = 2000;
constexpr int NNODES = NREAL + NVIRT;   // 32000
constexpr int NEDGES = 512000;
constexpr int STRIDE = 64;  // max tracked in-degree; Poisson(16): P(deg>64) ~ 1e-18

// Two-level CSR build geometry
constexpr int NSTAGE  = 2000;  // staging blocks in k_prep (verified path)
constexpr int NBINBLK = 250;   // binning blocks in k_prep, 2048 edges each
constexpr int NBIN    = 256;   // dst bins; bin = dst/125
constexpr int NPB     = 125;   // nodes per bin (256*125 = 32000)
constexpr int CAP     = 48;    // partition cell capacity; cell load ~Poisson(8), P(>48)~1e-22
// virtual nodes start at 30000 = 240*125 -> bins 240..255 own exactly the virtual range

typedef _Float16 half4 __attribute__((ext_vector_type(4)));

// ---------------- kernels ----------------

// k_prep: staging (blocks 0..1999, verified numerics) + edge partitioning
// (blocks 2000..2249). NO global atomics (round-3/4 evidence: 512k device-scope
// returning atomics = ~24MB fabric traffic, ~+25us). Each binning block owns
// edges [b*2048,(b+1)*2048) and scatters them into statically-owned partition
// cells part[(bin*256+b)*CAP ...] — ownership replaces atomic reservation.
// No memset dispatch: cnt/slots/new_nft are fully (re)written downstream;
// mark has been eliminated entirely (round-7 fusion).
__global__ __launch_bounds__(256) void k_prep(const float* __restrict__ features,
                                              const float* __restrict__ virtue,
                                              const int* __restrict__ cnodes,
                                              const int* __restrict__ src,
                                              const int* __restrict__ dst,
                                              _Float16* __restrict__ ndata,
                                              unsigned short* __restrict__ gHist,
                                              unsigned int* __restrict__ part) {
  if (blockIdx.x < NSTAGE) {
    // ---- staging path (identical numerics to all verified rounds) ----
    int i = blockIdx.x * 256 + threadIdx.x;          // 0..NEDGES-1
    int node = i >> 4;
    int q    = i & 15;
    const float4* srcp = (node < NREAL)
        ? (const float4*)(features + (long)cnodes[node] * DIM)
        : (const float4*)(virtue + (long)(node - NREAL) * DIM);
    float4 v = srcp[q];
    half4 h = { (_Float16)v.x, (_Float16)v.y, (_Float16)v.z, (_Float16)v.w };
    ((half4*)(ndata + (long)node * DIM))[q] = h;
    return;
  }

  // ---- binning path: one block owns 2048 contiguous edges (round-6 verified) ----
  __shared__ unsigned int hist[NBIN];
  __shared__ unsigned int cur[NBIN];
  int b   = blockIdx.x - NSTAGE;    // 0..249
  int tid = threadIdx.x;

  hist[tid] = 0;
  __syncthreads();

  int e0 = b * 2048 + tid * 8;      // 8 edges per thread, 32B-aligned int4 loads
  int4 sa = *(const int4*)(src + e0);
  int4 sb = *(const int4*)(src + e0 + 4);
  int4 da = *(const int4*)(dst + e0);
  int4 db = *(const int4*)(dst + e0 + 4);
  int ds8[8] = { da.x, da.y, da.z, da.w, db.x, db.y, db.z, db.w };
  int ss8[8] = { sa.x, sa.y, sa.z, sa.w, sb.x, sb.y, sb.z, sb.w };
  int bn8[8];
#pragma unroll
  for (int j = 0; j < 8; ++j) {
    bn8[j] = ds8[j] / NPB;                  // magic-mul for /125
    atomicAdd(&hist[bn8[j]], 1u);           // LDS atomic: on-CU
  }
  __syncthreads();

  // publish per-cell counts; init per-bin cursors to this block's cell base
  gHist[tid * 256 + b] = (unsigned short)hist[tid];
  cur[tid] = ((unsigned)tid * 256u + (unsigned)b) * CAP;
  __syncthreads();

#pragma unroll
  for (int j = 0; j < 8; ++j) {
    unsigned p   = atomicAdd(&cur[bn8[j]], 1u);   // LDS atomic
    unsigned lim = ((unsigned)bn8[j] * 256u + (unsigned)b) * CAP + CAP;
    if (p < lim)                                   // overflow guard (P~1e-17)
      part[p] = ((unsigned)ds8[j] << 15) | (unsigned)ss8[j];
  }
}

// k_binagg: fusion of bin-bucketing and round-1 aggregation (kills the 8MB
// slots round-trip, the mark machinery, and one dispatch boundary).
// Block B owns dst nodes [B*125, B*125+125). 1024 threads = 16 waves.
//  phase A: read own bin's partition cells (~2048 edges), LDS-prefix-scan cell
//           counts, binary-search cell membership, bucket into LDS slotbuf
//           via LDS atomics (round-6 verified scheme).
//  phase B: 16 waves aggregate all 125 owned nodes directly from slotbuf
//           (round-0/4 verified lane layout and accumulation), write new_nft.
//  Virtual-owner blocks (240..255) additionally export slots+cnt (compacted
//  by virtual index) for k_agg2.
__global__ __launch_bounds__(1024) void k_binagg(const unsigned short* __restrict__ gHist,
                                                 const unsigned int* __restrict__ part,
                                                 const _Float16* __restrict__ ndata,
                                                 int* __restrict__ cnt,
                                                 unsigned short* __restrict__ slots,
                                                 float* __restrict__ new_nft) {
  __shared__ unsigned short slotbuf[NPB * STRIDE];   // 16000 B
  __shared__ int            cntloc[NPB];
  __shared__ unsigned int   pre[257];

  int B = blockIdx.x, tid = threadIdx.x;
  if (tid < NPB) cntloc[tid] = 0;

  // cell counts for this bin (coalesced u16 row read), clamp to CAP
  if (tid < 256) {
    unsigned c = (tid < NBINBLK) ? (unsigned)gHist[B * 256 + tid] : 0u;
    if (c > CAP) c = CAP;
    pre[tid + 1] = c;
    if (tid == 0) pre[0] = 0;
  }
  __syncthreads();
  // Hillis-Steele inclusive scan over pre[1..256] (first 256 threads active;
  // all 1024 reach the barriers)
  for (int off = 1; off < 256; off <<= 1) {
    unsigned v = 0;
    if (tid >= off && tid < 256) v = pre[tid + 1 - off];
    __syncthreads();
    if (tid >= off && tid < 256) pre[tid + 1] += v;
    __syncthreads();
  }
  unsigned T = pre[256];                 // total edges in this bin (~2048)
  int base0 = B * NPB;

  // phase A: bucket (each thread ~2 edges)
  for (unsigned t = tid; t < T; t += 1024) {
    int lo = 0, hi = 255;                // largest blk with pre[blk] <= t
    while (lo < hi) { int mid = (lo + hi + 1) >> 1; if (pre[mid] <= t) lo = mid; else hi = mid - 1; }
    unsigned w = part[((unsigned)B * 256u + (unsigned)lo) * CAP + (t - pre[lo])];
    int d = (int)(w >> 15);
    int s = (int)(w & 0x7fffu);
    int r = d - base0;                            // in [0,125) by construction
    int pos = atomicAdd(&cntloc[r], 1);           // LDS atomic
    if (pos < STRIDE) slotbuf[r * STRIDE + pos] = (unsigned short)s;
  }
  __syncthreads();

  // phase B: aggregate all 125 owned nodes straight from LDS.
  // Lane layout (verified rounds 0/4): q = lane>>4 (edge sub-slot),
  // l = lane&15 (8B fp16 chunk = dims 4l..4l+3).
  int wave = tid >> 6;
  int lane = tid & 63;
  int q = lane >> 4;
  int l = lane & 15;
  const half4* nd = (const half4*)ndata;
  for (int r = wave; r < NPB; r += 16) {
    int deg = cntloc[r];
    if (deg > STRIDE) deg = STRIDE;               // safety clamp
    int myidx = (int)slotbuf[r * STRIDE + lane];  // lanes >= deg: garbage, never consumed
    float4 acc  = make_float4(0.f, 0.f, 0.f, 0.f);
    float4 acc2 = make_float4(0.f, 0.f, 0.f, 0.f);
#pragma unroll
    for (int u = 0; u < 8; ++u) {
      int ka = u * 8 + q;
      int kb = u * 8 + q + 4;
      int sa = __shfl(myidx, ka);
      int sb = __shfl(myidx, kb);
      if (ka < deg) {
        half4 v = nd[(long)sa * 16 + l];
        acc.x += (float)v.x; acc.y += (float)v.y; acc.z += (float)v.z; acc.w += (float)v.w;
      }
      if (kb < deg) {
        half4 v = nd[(long)sb * 16 + l];
        acc2.x += (float)v.x; acc2.y += (float)v.y; acc2.z += (float)v.z; acc2.w += (float)v.w;
      }
    }
    acc.x += acc2.x; acc.y += acc2.y; acc.z += acc2.z; acc.w += acc2.w;
    acc.x += __shfl_xor(acc.x, 16); acc.y += __shfl_xor(acc.y, 16);
    acc.z += __shfl_xor(acc.z, 16); acc.w += __shfl_xor(acc.w, 16);
    acc.x += __shfl_xor(acc.x, 32); acc.y += __shfl_xor(acc.y, 32);
    acc.z += __shfl_xor(acc.z, 32); acc.w += __shfl_xor(acc.w, 32);
    if (q == 0) {
      float inv = (deg > 0) ? 1.0f / (float)deg : 0.0f;
      acc.x *= inv; acc.y *= inv; acc.z *= inv; acc.w *= inv;
      ((float4*)new_nft)[(long)(base0 + r) * 16 + l] = acc;
    }
  }

  // virtual-owner export for k_agg2 (bins 240..255 hold exactly the virtual nodes)
  if (base0 >= NREAL) {
    int vbase = base0 - NREAL;
    unsigned int* gs = (unsigned int*)(slots + (long)vbase * STRIDE);
    const unsigned int* ls = (const unsigned int*)slotbuf;
    for (int k2 = tid; k2 < NPB * STRIDE / 2; k2 += 1024) gs[k2] = ls[k2];
    if (tid < NPB) cnt[vbase + tid] = cntloc[tid];
  }
}

// Round 2: only virtual nodes reach the output; replicate across 8 heads.
// cnt/slots are compact (indexed by virtual id). Verified structure (round 4).
__global__ __launch_bounds__(256) void k_agg2(const int* __restrict__ cnt,
                                              const unsigned short* __restrict__ slots,
                                              const float* __restrict__ new_nft,
                                              float* __restrict__ out) {
  int v = blockIdx.x * 4 + (threadIdx.x >> 6);
  if (v >= NVIRT) return;
  int lane = threadIdx.x & 63;
  int q = lane >> 4;
  int l = lane & 15;
  int deg = cnt[v];
  int myidx = (int)slots[(long)v * STRIDE + lane];
  if (deg > STRIDE) deg = STRIDE;
  float4 acc  = make_float4(0.f, 0.f, 0.f, 0.f);
  float4 acc2 = make_float4(0.f, 0.f, 0.f, 0.f);
  const float4* nf4 = (const float4*)new_nft;
#pragma unroll
  for (int u = 0; u < 8; ++u) {
    int ka = u * 8 + q;
    int kb = u * 8 + q + 4;
    int sa = __shfl(myidx, ka);
    int sb = __shfl(myidx, kb);
    if (ka < deg) {
      float4 x = nf4[(long)sa * 16 + l];
      acc.x += x.x; acc.y += x.y; acc.z += x.z; acc.w += x.w;
    }
    if (kb < deg) {
      float4 x = nf4[(long)sb * 16 + l];
      acc2.x += x.x; acc2.y += x.y; acc2.z += x.z; acc2.w += x.w;
    }
  }
  acc.x += acc2.x; acc.y += acc2.y; acc.z += acc2.z; acc.w += acc2.w;
  acc.x += __shfl_xor(acc.x, 16); acc.y += __shfl_xor(acc.y, 16);
  acc.z += __shfl_xor(acc.z, 16); acc.w += __shfl_xor(acc.w, 16);
  acc.x += __shfl_xor(acc.x, 32); acc.y += __shfl_xor(acc.y, 32);
  acc.z += __shfl_xor(acc.z, 32); acc.w += __shfl_xor(acc.w, 32);
  if (q == 0) {
    float inv = (deg > 0) ? 1.0f / (float)deg : 0.0f;
    acc.x *= inv; acc.y *= inv; acc.z *= inv; acc.w *= inv;
    float4* o4 = (float4*)out;
#pragma unroll
    for (int h = 0; h < HEADS; ++h)
      o4[((long)v * HEADS + h) * 16 + l] = acc;
  }
}

// ---------------- launch ----------------

extern "C" void kernel_launch(void* const* d_in, const int* in_sizes, int n_in,
                              void* d_out, int out_size, void* d_ws, size_t ws_size,
                              hipStream_t stream) {
  const float* features = (const float*)d_in[0];   // [VOCAB, 64]
  const float* virtue   = (const float*)d_in[1];   // [NVIRT, 64]
  const int*   cnodes   = (const int*)d_in[2];     // [NREAL]
  const int*   src      = (const int*)d_in[3];     // [NEDGES]
  const int*   dst      = (const int*)d_in[4];     // [NEDGES]
  float* out = (float*)d_out;                      // [NVIRT, 8, 64] fp32

  // workspace layout (offsets all 16B-aligned)
  float*          new_nft = (float*)d_ws;                              // 8.192 MB
  _Float16*       ndata   = (_Float16*)(new_nft + (long)NNODES * DIM); // 4.096 MB
  unsigned short* gHist   = (unsigned short*)(ndata + (long)NNODES * DIM); // [NBIN*256] u16, 128 KB
  unsigned int*   part    = (unsigned int*)(gHist + NBIN * 256);       // [NBIN*256*CAP] u32, 12.6 MB
  int*            cnt     = (int*)(part + (long)NBIN * 256 * CAP);     // [NVIRT] 8 KB
  unsigned short* slots   = (unsigned short*)(cnt + NVIRT);            // [NVIRT*STRIDE] u16, 256 KB

  const int B = 256;

  k_prep<<<NSTAGE + NBINBLK, B, 0, stream>>>(features, virtue, cnodes, src, dst,
                                             ndata, gHist, part);
  k_binagg<<<NBIN, 1024, 0, stream>>>(gHist, part, ndata, cnt, slots, new_nft);
  k_agg2<<<(NVIRT + 3) / 4, B, 0, stream>>>(cnt, slots, new_nft, out);
}